// Round 14
// baseline (266.035 us; speedup 1.0000x reference)
//
#include <hip/hip_runtime.h>
#include <hip/hip_bf16.h>
#include <climits>
#include <cstdint>
#include <cfloat>

#define NROWS   524288
#define KDIM    128
#define NGRAPH  64
#define NSTROKE 8192
#define EPSF    1e-5f

typedef __bf16 bf16x8 __attribute__((ext_vector_type(8)));
typedef float  f32x4  __attribute__((ext_vector_type(4)));

// ws layout (bytes)
#define WT_OFF    0                         // ushort bf16 Wt[256][128] (col-major)
#define CSUM_OFF  65536                     // float[256]
#define CSQ_OFF   66560                     // float[256]
#define ST_OFF    67584                     // int [8192][128] stroke max (int-key)
#define GT_OFF    (ST_OFF + (size_t)NSTROKE*KDIM*4) // int [64][128] graph max
#define XB_OFF    (GT_OFF + (size_t)NGRAPH*KDIM*4)  // ushort bf16 x[N][128], PRE-SWIZZLED
// XB ends at ~138.6 MB, well within ws (>=2GB per harness poison size)

__device__ __forceinline__ unsigned short f2bf(float f) {
  unsigned int u = __float_as_uint(f);
  u += 0x7fffu + ((u >> 16) & 1u);   // RNE
  return (unsigned short)(u >> 16);
}
// order-preserving float<->int key (for atomicMax)
__device__ __forceinline__ int fkey(float f) {
  int b = __float_as_int(f);
  return b >= 0 ? b : (b ^ 0x7fffffff);
}
__device__ __forceinline__ float fdec(int k) {
  int b = k >= 0 ? k : (k ^ 0x7fffffff);
  return __int_as_float(b);
}
__device__ __forceinline__ bf16x8 cvt8(f32x4 a, f32x4 b) {
  bf16x8 r;
  r[0] = (__bf16)a[0]; r[1] = (__bf16)a[1]; r[2] = (__bf16)a[2]; r[3] = (__bf16)a[3];
  r[4] = (__bf16)b[0]; r[5] = (__bf16)b[1]; r[6] = (__bf16)b[2]; r[7] = (__bf16)b[3];
  return r;
}

// async global->LDS, 16B per lane: LDS dest = wave-uniform base + lane*16,
// global src = per-lane address (guide §5 / m97 / m104).
typedef const __attribute__((address_space(1))) void* as1p;
typedef __attribute__((address_space(3))) void* as3p;
__device__ __forceinline__ void gload_lds16(const void* g, void* l) {
  __builtin_amdgcn_global_load_lds((as1p)g, (as3p)l, 16, 0, 0);
}

// ---------------- init: weights -> bf16 col-major; clear sums + max tables ----
__global__ void k_init(const float* __restrict__ Wmax, const float* __restrict__ Wsk,
                       unsigned char* __restrict__ ws) {
  unsigned short* wt = (unsigned short*)(ws + WT_OFF);
  float* csum = (float*)(ws + CSUM_OFF);
  float* csq  = (float*)(ws + CSQ_OFF);
  int* st = (int*)(ws + ST_OFF);
  int* gt = (int*)(ws + GT_OFF);
  int i = blockIdx.x * blockDim.x + threadIdx.x;
  const int total = NSTROKE * KDIM;   // 1048576
  for (; i < total; i += gridDim.x * blockDim.x) {
    st[i] = INT_MIN;
    if (i < NGRAPH * KDIM) gt[i] = INT_MIN;
    if (i < 256) { csum[i] = 0.f; csq[i] = 0.f; }
    if (i < 256 * KDIM) {
      int c = i / KDIM, k = i % KDIM;
      float w = (c < 128) ? Wsk[k * 128 + c] : Wmax[k * 128 + (c - 128)];
      wt[i] = f2bf(w);   // wt[c][k]
    }
  }
}

// ---------------- conv: x fp32 -> bf16, PRE-SWIZZLED rows, pure stream ---------
// Writes xb[row][ (kg ^ (row&7))*8 .. ] = x[row][kg*8 ..]. NT loads (read-once),
// normal stores (134MB -> L3-resident for k_pass1). kg-granule = 16B so store
// coalescing at line granularity is unaffected by the permutation.
__global__ __launch_bounds__(256) void k_conv(const float* __restrict__ x,
                                              unsigned char* __restrict__ ws) {
  unsigned short* xb = (unsigned short*)(ws + XB_OFF);
  int i = blockIdx.x * blockDim.x + threadIdx.x;   // one 8-float chunk per iter
  const int total = NROWS * (KDIM / 8);            // 8388608
  for (; i < total; i += gridDim.x * blockDim.x) {
    int row = i >> 4;
    int kg  = i & 15;
    const f32x4* src = (const f32x4*)(x + (size_t)row * KDIM + kg * 8);
    f32x4 a = __builtin_nontemporal_load(src);
    f32x4 b = __builtin_nontemporal_load(src + 1);
    int kgd = kg ^ (row & 7);
    *(bf16x8*)(xb + (size_t)row * KDIM + kgd * 8) = cvt8(a, b);
  }
}

// ---------------- pass1: 8-wave GEMM, global_load_lds staging, acc-direct max --
// R14 vs R13: staging is 2 x global_load_lds(16B) per wave per tile from the
// bf16 pre-swizzled copy (L3-hot): no staging VGPRs, no in-loop conversion,
// half the staged bytes. LDS layout/frag reads identical to R13 (linear dest +
// pre-swizzled source + XOR on read = rule #21). Epilogue R13-exact.
__global__ __launch_bounds__(512) void k_pass1(const int* __restrict__ batch,
                                               const int* __restrict__ stroke,
                                               unsigned char* __restrict__ ws) {
  __shared__ __align__(16) unsigned short xs[2][64 * 128];  // 2 x 16 KB
  const unsigned short* wt = (const unsigned short*)(ws + WT_OFF);
  const unsigned short* xb = (const unsigned short*)(ws + XB_OFF);
  float* csum = (float*)(ws + CSUM_OFF);
  float* csq  = (float*)(ws + CSQ_OFF);
  int* st = (int*)(ws + ST_OFF);
  int* gt = (int*)(ws + GT_OFF);

  const int tid  = threadIdx.x;
  const int lane = tid & 63;
  const int wv   = tid >> 6;   // wave 0..7
  const int lr   = lane & 15;
  const int lg   = lane >> 4;

  const int colbase = wv * 32;            // combined col base
  const bool isS = (wv < 4);
  const int* __restrict__ segp = isS ? stroke : batch;
  int* __restrict__ tab = isS ? st : gt;
  const int tcol = colbase - (isS ? 0 : 128);

  // B fragments: lane holds Wt[col = colbase+n*16+lr][k = ks*32+lg*8 ..+7]
  bf16x8 bfrag[4][2];
#pragma unroll
  for (int ks = 0; ks < 4; ++ks)
#pragma unroll
    for (int n = 0; n < 2; ++n)
      bfrag[ks][n] = *(const bf16x8*)(wt + (colbase + n * 16 + lr) * KDIM + ks * 32 + lg * 8);

  float sumn[2] = {0.f, 0.f};
  float sqn[2]  = {0.f, 0.f};
  int   curseg = -1;
  float runmax[2] = {-FLT_MAX, -FLT_MAX};

#define FLUSH()                                                               \
  if (curseg >= 0) {                                                          \
    _Pragma("unroll")                                                         \
    for (int n = 0; n < 2; ++n) {                                             \
      float f = runmax[n];                                                    \
      f = fmaxf(f, __shfl_xor(f, 16));                                        \
      f = fmaxf(f, __shfl_xor(f, 32));                                        \
      if (lg == 0) atomicMax(&tab[curseg * KDIM + tcol + n * 16 + lr], fkey(f)); \
    }                                                                         \
  }

  // wave w stages rows [w*8, w*8+8) of the tile: 2KB = 2 x 1KB issues
#define STAGE(T, B)                                                           \
  {                                                                           \
    const char* gb = (const char*)(xb + (size_t)(brow + (T) * 64 + wv * 8) * KDIM) + lane * 16; \
    char* lb = (char*)(&xs[B][(wv * 8) * KDIM]);                              \
    gload_lds16(gb, lb);                                                      \
    gload_lds16(gb + 1024, lb + 1024);                                        \
  }

  const int brow = blockIdx.x * 512;   // 8 tiles x 64 rows
  int segv, segnext = 0;

  STAGE(0, 0);
  segv = segp[brow + lane];
  __syncthreads();

  int cur = 0;
  for (int ti = 0; ti < 8; ++ti) {
    // issue next tile's async loads; they drain at the barrier below
    if (ti < 7) {
      STAGE(ti + 1, cur ^ 1);
      segnext = segp[brow + (ti + 1) * 64 + lane];
    }

    // ---- MFMA: 64 rows x 32 cols per wave, from xs[cur] ----
    f32x4 acc[4][2];
#pragma unroll
    for (int m = 0; m < 4; ++m)
#pragma unroll
      for (int n = 0; n < 2; ++n) { f32x4 z = {0.f, 0.f, 0.f, 0.f}; acc[m][n] = z; }

#pragma unroll
    for (int ks = 0; ks < 4; ++ks) {
      bf16x8 af[4];
#pragma unroll
      for (int m = 0; m < 4; ++m) {
        int r  = m * 16 + lr;
        int kg = ks * 4 + lg;
        af[m] = *(const bf16x8*)(xs[cur] + r * KDIM + ((kg ^ (r & 7)) << 3));
      }
#pragma unroll
      for (int m = 0; m < 4; ++m) {
        acc[m][0] = __builtin_amdgcn_mfma_f32_16x16x32_bf16(af[m], bfrag[ks][0], acc[m][0], 0, 0, 0);
        acc[m][1] = __builtin_amdgcn_mfma_f32_16x16x32_bf16(af[m], bfrag[ks][1], acc[m][1], 0, 0, 0);
      }
    }

    // ---- column sums/sumsq + tile col-max straight from accumulators ----
    float tm[2];
#pragma unroll
    for (int n = 0; n < 2; ++n) {
      float s = 0.f, q = 0.f, t = -FLT_MAX;
#pragma unroll
      for (int m = 0; m < 4; ++m)
#pragma unroll
        for (int rg = 0; rg < 4; ++rg) {
          float v = acc[m][n][rg];
          s += v; q = fmaf(v, v, q); t = fmaxf(t, v);
        }
      sumn[n] += s; sqn[n] += q; tm[n] = t;
    }

    // ---- acc-direct segment max (R13-exact) ----
    {
      int pv = __shfl_up(segv, 1);
      unsigned long long mask = __ballot(lane > 0 && pv != segv);
      if (mask == 0ull) {
        int seg0 = __shfl(segv, 0);
        if (seg0 == curseg) {
#pragma unroll
          for (int n = 0; n < 2; ++n) runmax[n] = fmaxf(runmax[n], tm[n]);
        } else {
          FLUSH();
          curseg = seg0;
#pragma unroll
          for (int n = 0; n < 2; ++n) runmax[n] = tm[n];
        }
      } else {
        unsigned long long rem = mask;
        int a = 0;
        while (true) {
          int b = rem ? (int)__builtin_ctzll(rem) : 64;
          int segr = __shfl(segv, a);
          float rm[2] = {-FLT_MAX, -FLT_MAX};
#pragma unroll
          for (int m = 0; m < 4; ++m)
#pragma unroll
            for (int rg = 0; rg < 4; ++rg) {
              int pos = m * 16 + lg * 4 + rg;
              bool in = (pos >= a) && (pos < b);
#pragma unroll
              for (int n = 0; n < 2; ++n)
                rm[n] = in ? fmaxf(rm[n], acc[m][n][rg]) : rm[n];
            }
          if (a == 0 && segr == curseg) {
#pragma unroll
            for (int n = 0; n < 2; ++n) runmax[n] = fmaxf(runmax[n], rm[n]);
          } else {
            FLUSH();
            curseg = segr;
#pragma unroll
            for (int n = 0; n < 2; ++n) runmax[n] = rm[n];
          }
          if (b >= 64) break;
          rem &= rem - 1; a = b;
        }
      }
    }

    // barrier drains the async stage (vmcnt) + protects xs[cur] reuse
    __syncthreads();
    if (ti < 7) segv = segnext;
    cur ^= 1;
  }

  FLUSH();   // final carried run

  // ---- finalize sums: reduce over the 4 k-group lanes, atomics at lg==0 ----
#pragma unroll
  for (int n = 0; n < 2; ++n) {
    float s = sumn[n], q = sqn[n];
    s += __shfl_xor(s, 16); s += __shfl_xor(s, 32);
    q += __shfl_xor(q, 16); q += __shfl_xor(q, 32);
    if (lg == 0) {
      atomicAdd(&csum[colbase + n * 16 + lr], s);
      atomicAdd(&csq [colbase + n * 16 + lr], q);
    }
  }
#undef FLUSH
#undef STAGE
}

// ---------------- out: gather + BN(affine)+ReLU on the fly + stream write ------
// (R2-exact)
__global__ __launch_bounds__(256) void k_out(const int* __restrict__ batch,
                                             const int* __restrict__ stroke,
                                             const float* __restrict__ g_max,
                                             const float* __restrict__ be_max,
                                             const float* __restrict__ g_sk,
                                             const float* __restrict__ be_sk,
                                             const unsigned char* __restrict__ ws,
                                             float* __restrict__ out) {
  const float* csum = (const float*)(ws + CSUM_OFF);
  const float* csq  = (const float*)(ws + CSQ_OFF);
  const int* st = (const int*)(ws + ST_OFF);
  const int* gt = (const int*)(ws + GT_OFF);

  const int lane = threadIdx.x & 63;
  const int wvid = blockIdx.x * 4 + (threadIdx.x >> 6);
  const int row0 = wvid * 64;
  const bool isS = lane < 32;
  const int  cg  = (isS ? lane : lane - 32) * 4;
  const int* tab  = isS ? st : gt;
  const int* idxp = isS ? stroke : batch;
  const float* gv = isS ? g_sk : g_max;
  const float* bv = isS ? be_sk : be_max;

  const float invN = 1.0f / (float)NROWS;
  f32x4 mu, sc, bb;
#pragma unroll
  for (int j = 0; j < 4; ++j) {
    int cc = (isS ? 0 : 128) + cg + j;
    float m  = csum[cc] * invN;
    float vr = csq[cc] * invN - m * m;
    mu[j] = m;
    sc[j] = gv[cg + j] * rsqrtf(vr + EPSF);
    bb[j] = bv[cg + j];
  }

  f32x4* out4 = (f32x4*)out;
#pragma unroll 4
  for (int r = 0; r < 64; ++r) {
    int row = row0 + r;
    int seg = idxp[row];
    const int4 k4 = *(const int4*)(tab + (size_t)seg * KDIM + cg);
    f32x4 v;
    v[0] = fdec(k4.x); v[1] = fdec(k4.y); v[2] = fdec(k4.z); v[3] = fdec(k4.w);
#pragma unroll
    for (int j = 0; j < 4; ++j) v[j] = fmaxf(0.f, (v[j] - mu[j]) * sc[j] + bb[j]);
    __builtin_nontemporal_store(v, &out4[(size_t)row * 64 + lane]);
  }
}

extern "C" void kernel_launch(void* const* d_in, const int* in_sizes, int n_in,
                              void* d_out, int out_size, void* d_ws, size_t ws_size,
                              hipStream_t stream) {
  const float* x      = (const float*)d_in[0];
  const int*   batch  = (const int*)d_in[1];
  const int*   stroke = (const int*)d_in[2];
  const float* Wmax   = (const float*)d_in[3];
  const float* g_max  = (const float*)d_in[5];
  const float* be_max = (const float*)d_in[6];
  const float* Wsk    = (const float*)d_in[7];
  const float* g_sk   = (const float*)d_in[9];
  const float* be_sk  = (const float*)d_in[10];
  unsigned char* ws = (unsigned char*)d_ws;
  float* out = (float*)d_out;

  k_init <<<2048, 512, 0, stream>>>(Wmax, Wsk, ws);
  k_conv <<<2048, 256, 0, stream>>>(x, ws);
  k_pass1<<<1024, 512, 0, stream>>>(batch, stroke, ws);
  k_out  <<<2048, 256, 0, stream>>>(batch, stroke, g_max, be_max, g_sk, be_sk, ws, out);
}